// Round 13
// baseline (354.234 us; speedup 1.0000x reference)
//
#include <hip/hip_runtime.h>
#include <math.h>

#define N_NODES 50000
#define E_EDGES 600000
#define D_DIM 128
#define OUT_DIM 40
#define N_ITERS 5
#define GAMMA_C 0.1f
#define EPS_C 0.1f
#define MAXDEG 48                // bucket slots/node; P(Poisson(12)>48) ~ 3e-15
#define SCAN_BLOCKS 196          // 196*256 = 50176 >= N_NODES
#define GEMM_BLOCKS 391          // ceil(50000/128)  (embed kernel, 128-row tiles)
#define TILE_R 48                // fused-iteration tile rows
#define CONV_BLOCKS 1042         // ceil(50000/48)
#define EDGE_BLOCKS_C 586        // ceil(600000/1024): 4 edges/thread (r2-proven)

typedef short v8s __attribute__((ext_vector_type(8)));   // 8 bf16 (4 VGPRs)
typedef float v4f __attribute__((ext_vector_type(4)));   // MFMA accumulator
typedef unsigned int uint;
typedef unsigned short ushort;

__device__ __forceinline__ ushort f2bf(float f) {        // RNE fp32->bf16
    union { float f; uint u; } v; v.f = f;
    uint u = v.u;
    uint r = 0x7fffu + ((u >> 16) & 1u);
    return (ushort)((u + r) >> 16);
}
__device__ __forceinline__ float bf2f(ushort h) {
    union { uint u; float f; } v; v.u = ((uint)h) << 16;
    return v.f;
}
__device__ __forceinline__ float bflo(uint u) {
    union { uint u; float f; } v; v.u = u << 16; return v.f;
}
__device__ __forceinline__ float bfhi(uint u) {
    union { uint u; float f; } v; v.u = u & 0xffff0000u; return v.f;
}

// tanh(x) = 1 - 2/(e^{2x}+1). v_exp + v_rcp (~5 ops) vs libm tanhf (~40+).
__device__ __forceinline__ float tanh_fast(float x) {
    float e = __expf(x + x);
    return 1.0f - 2.0f * __builtin_amdgcn_rcpf(e + 1.0f);
}

// ---------------------------------------------------------------------------
// Combined (once): zero cursor[N] + weight prep to bf16.
// ---------------------------------------------------------------------------
__global__ __launch_bounds__(256) void zero_prep_kernel(int* __restrict__ cursor,
                                                        const float* __restrict__ Wemb,
                                                        const float* __restrict__ Wlin,
                                                        const float* __restrict__ Wanti,
                                                        const float* __restrict__ Wout,
                                                        ushort* __restrict__ WembH,
                                                        ushort* __restrict__ Wcat2H,
                                                        ushort* __restrict__ WoutH) {
    int i = blockIdx.x * 256 + threadIdx.x;
    if (i < N_NODES) cursor[i] = 0;
    if (i < D_DIM * D_DIM) {
        int r = i >> 7, c = i & 127;
        WembH[i] = f2bf(Wemb[i]);
        float a = Wanti[r * 128 + c] - Wanti[c * 128 + r];
        if (r == c) a -= GAMMA_C;
        Wcat2H[r * 256 + c]       = f2bf(a);
        Wcat2H[r * 256 + 128 + c] = f2bf(Wlin[r * 128 + c]);
        if (i < 48 * 128) WoutH[i] = (r < OUT_DIM) ? f2bf(Wout[r * 128 + c]) : (ushort)0;
    }
}

// ---------------------------------------------------------------------------
// MERGED: embed GEMM (blocks [0,391)) + edge scatter (blocks [391,977)).
// scatter: 4 strided edges/thread. embed: xh write through LDS (full-line).
// ---------------------------------------------------------------------------
__global__ __launch_bounds__(256) void build_embed_kernel(
        const float* __restrict__ Xf, const ushort* __restrict__ Wh,
        const float* __restrict__ bias, ushort* __restrict__ xH,
        const int* __restrict__ src, const int* __restrict__ dst,
        const float* __restrict__ ew, int* __restrict__ cursor,
        int2* __restrict__ es2, int bucketMode, int M) {
    __shared__ ushort Xs[128 * 128];          // 32 KB (embed blocks only)
    const int tid = threadIdx.x;

    if (blockIdx.x >= GEMM_BLOCKS) {
        // ---- scatter role: 4 strided edges/thread ----
        int base = (blockIdx.x - GEMM_BLOCKS) * 1024 + tid;
#pragma unroll
        for (int k = 0; k < 4; ++k) {
            int e = base + k * 256;
            if (e < E_EDGES) {
                int d = dst[e];
                int pos = atomicAdd(&cursor[d], 1);
                int2 rec = make_int2(src[e], __float_as_int(ew[e]));
                if (bucketMode) {
                    if (pos < MAXDEG) es2[d * MAXDEG + pos] = rec;
                } else {
                    es2[pos] = rec;
                }
            }
        }
        return;
    }

    // ---- embed role ----
    const int rowBase = blockIdx.x * 128;
#pragma unroll
    for (int p = 0; p < 8; ++p) {
        int cid = p * 256 + tid;
        int r = cid >> 4, c8 = cid & 15;
        int gr = rowBase + r;
        uint4 val = make_uint4(0, 0, 0, 0);
        if (gr < M) {
            const float* ptr = Xf + (size_t)gr * 128 + c8 * 8;
            float4 f0 = *(const float4*)ptr;
            float4 f1 = *(const float4*)(ptr + 4);
            val.x = (uint)f2bf(f0.x) | ((uint)f2bf(f0.y) << 16);
            val.y = (uint)f2bf(f0.z) | ((uint)f2bf(f0.w) << 16);
            val.z = (uint)f2bf(f1.x) | ((uint)f2bf(f1.y) << 16);
            val.w = (uint)f2bf(f1.z) | ((uint)f2bf(f1.w) << 16);
        }
        *(uint4*)(Xs + r * 128 + ((c8 ^ (r & 7)) << 3)) = val;
    }
    __syncthreads();

    const int lane = tid & 63;
    const int wv = tid >> 6;
    const int wrow = (wv & 1) * 64;
    const int wcol = (wv >> 1) * 64;
    const int l16 = lane & 15;
    const int q = lane >> 4;

    v4f acc[4][4];
#pragma unroll
    for (int i = 0; i < 4; ++i)
#pragma unroll
        for (int j = 0; j < 4; ++j) { v4f z = {0.f,0.f,0.f,0.f}; acc[i][j] = z; }

#pragma unroll
    for (int ks = 0; ks < 4; ++ks) {
        const int chunk = ks * 4 + q;
        v8s a[4], b[4];
#pragma unroll
        for (int i = 0; i < 4; ++i) {
            int m = wrow + i * 16 + l16;
            a[i] = *(const v8s*)(Xs + m * 128 + ((chunk ^ (m & 7)) << 3));
        }
#pragma unroll
        for (int j = 0; j < 4; ++j)
            b[j] = *(const v8s*)(Wh + (size_t)(wcol + j * 16 + l16) * 128 + chunk * 8);
#pragma unroll
        for (int i = 0; i < 4; ++i)
#pragma unroll
            for (int j = 0; j < 4; ++j)
                acc[i][j] = __builtin_amdgcn_mfma_f32_16x16x32_bf16(a[i], b[j], acc[i][j], 0, 0, 0);
    }

    // all waves done reading Xs before C overwrites it
    __syncthreads();

    // ---- C -> Xs (swizzled, bias applied) ----
#pragma unroll
    for (int j = 0; j < 4; ++j) {
        int col = wcol + j * 16 + l16;
        float bj = bias[col];
        const int csw = col >> 3, clo = col & 7;
#pragma unroll
        for (int i = 0; i < 4; ++i) {
            int trB = wrow + i * 16 + q * 4;
#pragma unroll
            for (int r = 0; r < 4; ++r) {
                int tr = trB + r;
                Xs[tr * 128 + (((csw ^ (tr & 7)) << 3) | clo)] = f2bf(acc[i][j][r] + bj);
            }
        }
    }
    __syncthreads();

    // ---- coalesced stage-out: full 64B lines ----
#pragma unroll
    for (int p = 0; p < 8; ++p) {
        int cid = p * 256 + tid;              // 2048 uint4
        int r = cid >> 4, c8 = cid & 15;
        int gr = rowBase + r;
        if (gr < M) {
            uint4 val = *(const uint4*)(Xs + r * 128 + ((c8 ^ (r & 7)) << 3));
            *(uint4*)(xH + (size_t)gr * 128 + c8 * 8) = val;
        }
    }
}

// ---------------------------------------------------------------------------
// FUSED per-iteration kernel: 48-ROW tiles, 512 threads.
// r12: 64-row/782 blocks = 3.05 blocks/CU = 24 waves (occ 27.8%), 1.79 TB/s
// effective vs 2.08 demonstrated (r8). 48-row: 1042 blocks, LDS 2x12KB ->
// wave-slot cap 4 blocks/CU = 32 resident waves (+33%), finer drain tail.
// Bucket es2 reads are per-node (tile-size independent). Depth-4 gather +
// LDS stage-out (full-line writes) kept from r11/r12.
// ---------------------------------------------------------------------------
__global__ __launch_bounds__(512) void gather_conv_update(
        const ushort* __restrict__ xin, ushort* __restrict__ xout,
        const int2* __restrict__ es2, const int* __restrict__ rowStart,
        const int* __restrict__ rowEnd, const ushort* __restrict__ Wcat2,
        const float* __restrict__ bconv, const ushort* __restrict__ WoutH,
        const float* __restrict__ bout, float* __restrict__ out,
        int doOut, int bucketMode, int esCap, int M) {
    __shared__ ushort Xs0[TILE_R * 128];      // agg tile -> x_new tile (12 KB)
    __shared__ ushort Xs1[TILE_R * 128];      // xin tile              (12 KB)
    const int tid = threadIdx.x;
    const int rowBase = blockIdx.x * TILE_R;

    // ---- stage xin tile (coalesced, swizzled): 768 uint4 ----
#pragma unroll
    for (int p = 0; p < 2; ++p) {
        int cid = p * 512 + tid;
        if (cid < TILE_R * 16) {
            int r = cid >> 4, c8 = cid & 15;
            int gr = rowBase + r;
            uint4 xv = make_uint4(0, 0, 0, 0);
            if (gr < M) xv = *(const uint4*)(xin + (size_t)gr * 128 + c8 * 8);
            *(uint4*)(Xs1 + r * 128 + ((c8 ^ (r & 7)) << 3)) = xv;
        }
    }

    // ---- gather phase: 16 lanes/node, 32 groups; pass1 covers rows 32-47 ----
    const int q16 = tid & 15;                 // elems [q16*8, q16*8+8)
    const int nb = tid >> 4;                  // group id 0..31
    const int gb = tid & 48;                  // group-base lane within wave
    for (int pass = 0; pass < 2; ++pass) {
        int r = pass * 32 + nb;               // local row
        if (r >= TILE_R) break;               // wave-uniform (nb>=16 in pass 1)
        int gr = rowBase + r;
        float sA[8] = {0,0,0,0,0,0,0,0};
        float sB[8] = {0,0,0,0,0,0,0,0};
        int e0 = 0, deg = 0;
        if (gr < M) {
            if (bucketMode) { e0 = gr * MAXDEG; deg = rowEnd[gr]; }
            else            { e0 = rowStart[gr]; deg = rowEnd[gr] - e0; }
        }
        for (int base = 0; base < deg; base += 16) {
            // one coalesced bulk-load of up to 16 edge records for the group
            int idx = e0 + base + q16;
            int2 myE = es2[idx < esCap ? idx : esCap - 1];
            int cnt = deg - base; if (cnt > 16) cnt = 16;
            int k = 0;
            for (; k + 4 <= cnt; k += 4) {
                int s0 = __shfl(myE.x, gb + k + 0);
                int s1 = __shfl(myE.x, gb + k + 1);
                int s2 = __shfl(myE.x, gb + k + 2);
                int s3 = __shfl(myE.x, gb + k + 3);
                float w0 = __int_as_float(__shfl(myE.y, gb + k + 0));
                float w1 = __int_as_float(__shfl(myE.y, gb + k + 1));
                float w2 = __int_as_float(__shfl(myE.y, gb + k + 2));
                float w3 = __int_as_float(__shfl(myE.y, gb + k + 3));
                uint4 v0 = *(const uint4*)(xin + (size_t)s0 * 128 + q16 * 8);
                uint4 v1 = *(const uint4*)(xin + (size_t)s1 * 128 + q16 * 8);
                uint4 v2 = *(const uint4*)(xin + (size_t)s2 * 128 + q16 * 8);
                uint4 v3 = *(const uint4*)(xin + (size_t)s3 * 128 + q16 * 8);
                sA[0] = fmaf(w0, bflo(v0.x), sA[0]); sA[1] = fmaf(w0, bfhi(v0.x), sA[1]);
                sA[2] = fmaf(w0, bflo(v0.y), sA[2]); sA[3] = fmaf(w0, bfhi(v0.y), sA[3]);
                sA[4] = fmaf(w0, bflo(v0.z), sA[4]); sA[5] = fmaf(w0, bfhi(v0.z), sA[5]);
                sA[6] = fmaf(w0, bflo(v0.w), sA[6]); sA[7] = fmaf(w0, bfhi(v0.w), sA[7]);
                sB[0] = fmaf(w1, bflo(v1.x), sB[0]); sB[1] = fmaf(w1, bfhi(v1.x), sB[1]);
                sB[2] = fmaf(w1, bflo(v1.y), sB[2]); sB[3] = fmaf(w1, bfhi(v1.y), sB[3]);
                sB[4] = fmaf(w1, bflo(v1.z), sB[4]); sB[5] = fmaf(w1, bfhi(v1.z), sB[5]);
                sB[6] = fmaf(w1, bflo(v1.w), sB[6]); sB[7] = fmaf(w1, bfhi(v1.w), sB[7]);
                sA[0] = fmaf(w2, bflo(v2.x), sA[0]); sA[1] = fmaf(w2, bfhi(v2.x), sA[1]);
                sA[2] = fmaf(w2, bflo(v2.y), sA[2]); sA[3] = fmaf(w2, bfhi(v2.y), sA[3]);
                sA[4] = fmaf(w2, bflo(v2.z), sA[4]); sA[5] = fmaf(w2, bfhi(v2.z), sA[5]);
                sA[6] = fmaf(w2, bflo(v2.w), sA[6]); sA[7] = fmaf(w2, bfhi(v2.w), sA[7]);
                sB[0] = fmaf(w3, bflo(v3.x), sB[0]); sB[1] = fmaf(w3, bfhi(v3.x), sB[1]);
                sB[2] = fmaf(w3, bflo(v3.y), sB[2]); sB[3] = fmaf(w3, bfhi(v3.y), sB[3]);
                sB[4] = fmaf(w3, bflo(v3.z), sB[4]); sB[5] = fmaf(w3, bfhi(v3.z), sB[5]);
                sB[6] = fmaf(w3, bflo(v3.w), sB[6]); sB[7] = fmaf(w3, bfhi(v3.w), sB[7]);
            }
            for (; k < cnt; ++k) {
                int s = __shfl(myE.x, gb + k);
                float w = __int_as_float(__shfl(myE.y, gb + k));
                uint4 v = *(const uint4*)(xin + (size_t)s * 128 + q16 * 8);
                sA[0] = fmaf(w, bflo(v.x), sA[0]); sA[1] = fmaf(w, bfhi(v.x), sA[1]);
                sA[2] = fmaf(w, bflo(v.y), sA[2]); sA[3] = fmaf(w, bfhi(v.y), sA[3]);
                sA[4] = fmaf(w, bflo(v.z), sA[4]); sA[5] = fmaf(w, bfhi(v.z), sA[5]);
                sA[6] = fmaf(w, bflo(v.w), sA[6]); sA[7] = fmaf(w, bfhi(v.w), sA[7]);
            }
        }
        uint4 o;
        o.x = (uint)f2bf(sA[0] + sB[0]) | ((uint)f2bf(sA[1] + sB[1]) << 16);
        o.y = (uint)f2bf(sA[2] + sB[2]) | ((uint)f2bf(sA[3] + sB[3]) << 16);
        o.z = (uint)f2bf(sA[4] + sB[4]) | ((uint)f2bf(sA[5] + sB[5]) << 16);
        o.w = (uint)f2bf(sA[6] + sB[6]) | ((uint)f2bf(sA[7] + sB[7]) << 16);
        *(uint4*)(Xs0 + r * 128 + ((q16 ^ (r & 7)) << 3)) = o;
    }
    __syncthreads();

    const int lane = tid & 63;
    const int wv = tid >> 6;                  // wave col-block: cols [wv*16, wv*16+16)
    const int l16 = lane & 15;
    const int q = lane >> 4;

    v4f acc[3];
#pragma unroll
    for (int i = 0; i < 3; ++i) { v4f z = {0.f,0.f,0.f,0.f}; acc[i] = z; }

    // 8 K-chunks: ks<4 -> agg x W_lin (wOff=128); ks>=4 -> x x A (wOff=0)
#pragma unroll
    for (int ks = 0; ks < 8; ++ks) {
        const ushort* Xsrc = (ks < 4) ? Xs0 : Xs1;
        const int wOff = (ks < 4) ? 128 : 0;
        const int chunk = (ks & 3) * 4 + q;
        v8s a[3], b;
#pragma unroll
        for (int i = 0; i < 3; ++i) {
            int m = i * 16 + l16;             // rows 0..47
            a[i] = *(const v8s*)(Xsrc + m * 128 + ((chunk ^ (m & 7)) << 3));
        }
        b = *(const v8s*)(Wcat2 + (size_t)(wv * 16 + l16) * 256 + wOff + chunk * 8);
#pragma unroll
        for (int i = 0; i < 3; ++i)
            acc[i] = __builtin_amdgcn_mfma_f32_16x16x32_bf16(a[i], b, acc[i], 0, 0, 0);
    }

    // all waves done reading Xs0 (agg) before it is overwritten with x_new
    __syncthreads();

    // ---- epilogue: x-old from Xs1; h -> Xs0 (swizzled, same layout) ----
    {
        int col = wv * 16 + l16;
        float bj = bconv[col];
        const int csw = col >> 3, clo = col & 7;
#pragma unroll
        for (int i = 0; i < 3; ++i) {
            int trB = i * 16 + q * 4;
#pragma unroll
            for (int r = 0; r < 4; ++r) {
                int tr = trB + r;
                int li = tr * 128 + (((csw ^ (tr & 7)) << 3) | clo);
                float conv = acc[i][r] + bj;
                float xv = bf2f(Xs1[li]) + EPS_C * tanh_fast(conv);
                Xs0[li] = f2bf(xv);
            }
        }
    }
    __syncthreads();

    // ---- coalesced stage-out: full 64B lines (mirror of stage-in) ----
#pragma unroll
    for (int p = 0; p < 2; ++p) {
        int cid = p * 512 + tid;
        if (cid < TILE_R * 16) {
            int r = cid >> 4, c8 = cid & 15;
            int gr = rowBase + r;
            if (gr < M) {
                uint4 val = *(const uint4*)(Xs0 + r * 128 + ((c8 ^ (r & 7)) << 3));
                *(uint4*)(xout + (size_t)gr * 128 + c8 * 8) = val;
            }
        }
    }

    if (doOut) {
        // Xs0 holds x_new (stage-out was read-only); readout from Xs0.
        // 48 rows x 48 padded cols = 9 (rg,cg) 16x16 tasks over 8 waves.
        for (int t = wv; t < 9; t += 8) {
            int rg = t / 3, cg = t % 3;
            v4f acc2 = {0.f, 0.f, 0.f, 0.f};
#pragma unroll
            for (int ks = 0; ks < 4; ++ks) {
                const int chunk = ks * 4 + q;
                int m = rg * 16 + l16;
                v8s a2 = *(const v8s*)(Xs0 + m * 128 + ((chunk ^ (m & 7)) << 3));
                v8s b2 = *(const v8s*)(WoutH + (size_t)(cg * 16 + l16) * 128 + chunk * 8);
                acc2 = __builtin_amdgcn_mfma_f32_16x16x32_bf16(a2, b2, acc2, 0, 0, 0);
            }
            int col = cg * 16 + l16;
            if (col < OUT_DIM) {
                float bj = bout[col];
                int grB = rowBase + rg * 16 + q * 4;
#pragma unroll
                for (int r = 0; r < 4; ++r) {
                    int gr = grB + r;
                    if (gr < M) out[(size_t)gr * OUT_DIM + col] = acc2[r] + bj;
                }
            }
        }
    }
}

// ---------------------------------------------------------------------------
// Exact-CSR fallback chain (used only if ws_size can't hold the buckets)
// ---------------------------------------------------------------------------
__global__ __launch_bounds__(256) void hist_kernel(const int* __restrict__ dst,
                                                   int* __restrict__ cnt) {
    int base = blockIdx.x * 1024 + threadIdx.x;
#pragma unroll
    for (int k = 0; k < 4; ++k) {
        int e = base + k * 256;
        if (e < E_EDGES) atomicAdd(&cnt[dst[e]], 1);
    }
}

__global__ __launch_bounds__(256) void scan_phase1(const int* __restrict__ deg,
                                                   int* __restrict__ localEx,
                                                   int* __restrict__ blockSums) {
    __shared__ int tmp[256];
    const int t = threadIdx.x;
    const int i = blockIdx.x * 256 + t;
    int v = (i < N_NODES) ? deg[i] : 0;
    tmp[t] = v;
    __syncthreads();
#pragma unroll
    for (int off = 1; off < 256; off <<= 1) {
        int u = (t >= off) ? tmp[t - off] : 0;
        __syncthreads();
        tmp[t] += u;
        __syncthreads();
    }
    if (i < N_NODES) localEx[i] = tmp[t] - v;
    if (t == 255) blockSums[blockIdx.x] = tmp[255];
}

__global__ __launch_bounds__(256) void scan_phase23(int* __restrict__ rowStart,
                                                    const int* __restrict__ blockSums,
                                                    int* __restrict__ cursor) {
    __shared__ int tmp[256];
    __shared__ int offs;
    const int t = threadIdx.x;
    int v = (t < SCAN_BLOCKS) ? blockSums[t] : 0;
    tmp[t] = v;
    __syncthreads();
#pragma unroll
    for (int off = 1; off < 256; off <<= 1) {
        int u = (t >= off) ? tmp[t - off] : 0;
        __syncthreads();
        tmp[t] += u;
        __syncthreads();
    }
    if (t == blockIdx.x) offs = tmp[t] - v;
    __syncthreads();
    const int i = blockIdx.x * 256 + t;
    if (i < N_NODES) {
        int val = rowStart[i] + offs;
        rowStart[i] = val;
        cursor[i] = val;
    }
}

extern "C" void kernel_launch(void* const* d_in, const int* in_sizes, int n_in,
                              void* d_out, int out_size, void* d_ws, size_t ws_size,
                              hipStream_t stream) {
    const float* x_in   = (const float*)d_in[0];
    const int*   ei     = (const int*)  d_in[1];   // (2,E) int32: src=ei, dst=ei+E
    const float* ew     = (const float*)d_in[2];
    const float* W_emb  = (const float*)d_in[3];
    const float* b_emb  = (const float*)d_in[4];
    const float* W_lin  = (const float*)d_in[5];
    const float* W_anti = (const float*)d_in[6];
    const float* b_conv = (const float*)d_in[7];
    const float* W_out  = (const float*)d_in[8];
    const float* b_out  = (const float*)d_in[9];
    float* out = (float*)d_out;

    // workspace: xhA | xhB | WembH | Wcat2H | WoutH | rowStart | cursor |
    //            es2 (bucket: N*MAXDEG int2 = 19.2MB; CSR: E int2) | blockSums
    ushort* xhA    = (ushort*)d_ws;
    ushort* xhB    = xhA + (size_t)N_NODES * D_DIM;
    ushort* WembH  = xhB + (size_t)N_NODES * D_DIM;
    ushort* Wcat2H = WembH + D_DIM * D_DIM;
    ushort* WoutH  = Wcat2H + 2 * D_DIM * D_DIM;
    int*    rowStart = (int*)(WoutH + 48 * D_DIM);
    int*    cursor   = rowStart + N_NODES;
    int2*   es2      = (int2*)(cursor + N_NODES);
    int*    blockSums = (int*)(es2 + E_EDGES);   // CSR mode only

    const int* src = ei;
    const int* dst = ei + E_EDGES;

    // bucket layout fits? fixed prefix + N*MAXDEG records (+ slack)
    size_t fixedBytes = (size_t)((char*)es2 - (char*)d_ws);
    size_t bucketBytes = (size_t)N_NODES * MAXDEG * sizeof(int2);
    int bucket = (ws_size >= fixedBytes + bucketBytes + 4096) ? 1 : 0;
    int esCap = bucket ? N_NODES * MAXDEG : E_EDGES;

    // ---- front-end ----
    zero_prep_kernel<<<SCAN_BLOCKS, 256, 0, stream>>>(cursor, W_emb, W_lin, W_anti,
                                                      W_out, WembH, Wcat2H, WoutH);
    if (!bucket) {
        hist_kernel<<<EDGE_BLOCKS_C, 256, 0, stream>>>(dst, cursor);
        scan_phase1<<<SCAN_BLOCKS, 256, 0, stream>>>(cursor, rowStart, blockSums);
        scan_phase23<<<SCAN_BLOCKS, 256, 0, stream>>>(rowStart, blockSums, cursor);
    }
    build_embed_kernel<<<GEMM_BLOCKS + EDGE_BLOCKS_C, 256, 0, stream>>>(
        x_in, WembH, b_emb, xhA, src, dst, ew, cursor, es2, bucket, N_NODES);
    // after build: bucket -> cursor[d] = degree; CSR -> cursor[d] = row end

    // ---- iterations: ONE fused dispatch each, ping-pong xhA/xhB ----
    ushort* bufs[2] = { xhA, xhB };
    for (int it = 0; it < N_ITERS; ++it) {
        gather_conv_update<<<CONV_BLOCKS, 512, 0, stream>>>(
            bufs[it & 1], bufs[(it + 1) & 1], es2, rowStart, cursor,
            Wcat2H, b_conv, WoutH, b_out, out,
            (it == N_ITERS - 1) ? 1 : 0, bucket, esCap, N_NODES);
    }
}

// Round 14
// 321.161 us; speedup vs baseline: 1.1030x; 1.1030x over previous
//
#include <hip/hip_runtime.h>
#include <math.h>

#define N_NODES 50000
#define E_EDGES 600000
#define D_DIM 128
#define OUT_DIM 40
#define N_ITERS 5
#define GAMMA_C 0.1f
#define EPS_C 0.1f
#define MAXDEG 48                // bucket slots/node; P(Poisson(12)>48) ~ 3e-15
#define SCAN_BLOCKS 196          // 196*256 = 50176 >= N_NODES
#define GEMM_BLOCKS 391          // ceil(50000/128)  (embed kernel, 128-row tiles)
#define CONV_BLOCKS 782          // ceil(50000/64)   (fused iteration, 64-row tiles)
#define EDGE_BLOCKS_C 586        // ceil(600000/1024): 4 edges/thread (r2-proven)

typedef short v8s __attribute__((ext_vector_type(8)));   // 8 bf16 (4 VGPRs)
typedef float v4f __attribute__((ext_vector_type(4)));   // MFMA accumulator
typedef unsigned int uint;
typedef unsigned short ushort;

__device__ __forceinline__ ushort f2bf(float f) {        // RNE fp32->bf16
    union { float f; uint u; } v; v.f = f;
    uint u = v.u;
    uint r = 0x7fffu + ((u >> 16) & 1u);
    return (ushort)((u + r) >> 16);
}
__device__ __forceinline__ float bf2f(ushort h) {
    union { uint u; float f; } v; v.u = ((uint)h) << 16;
    return v.f;
}
__device__ __forceinline__ float bflo(uint u) {
    union { uint u; float f; } v; v.u = u << 16; return v.f;
}
__device__ __forceinline__ float bfhi(uint u) {
    union { uint u; float f; } v; v.u = u & 0xffff0000u; return v.f;
}

// tanh(x) = 1 - 2/(e^{2x}+1). v_exp + v_rcp (~5 ops) vs libm tanhf (~40+).
__device__ __forceinline__ float tanh_fast(float x) {
    float e = __expf(x + x);
    return 1.0f - 2.0f * __builtin_amdgcn_rcpf(e + 1.0f);
}

// ---------------------------------------------------------------------------
// Combined (once): zero cursor[N] + weight prep to bf16.
// ---------------------------------------------------------------------------
__global__ __launch_bounds__(256) void zero_prep_kernel(int* __restrict__ cursor,
                                                        const float* __restrict__ Wemb,
                                                        const float* __restrict__ Wlin,
                                                        const float* __restrict__ Wanti,
                                                        const float* __restrict__ Wout,
                                                        ushort* __restrict__ WembH,
                                                        ushort* __restrict__ Wcat2H,
                                                        ushort* __restrict__ WoutH) {
    int i = blockIdx.x * 256 + threadIdx.x;
    if (i < N_NODES) cursor[i] = 0;
    if (i < D_DIM * D_DIM) {
        int r = i >> 7, c = i & 127;
        WembH[i] = f2bf(Wemb[i]);
        float a = Wanti[r * 128 + c] - Wanti[c * 128 + r];
        if (r == c) a -= GAMMA_C;
        Wcat2H[r * 256 + c]       = f2bf(a);
        Wcat2H[r * 256 + 128 + c] = f2bf(Wlin[r * 128 + c]);
        if (i < 48 * 128) WoutH[i] = (r < OUT_DIM) ? f2bf(Wout[r * 128 + c]) : (ushort)0;
    }
}

// ---------------------------------------------------------------------------
// MERGED: embed GEMM (blocks [0,391)) + edge scatter (blocks [391,977)).
// scatter: 4 strided edges/thread. embed: xh write through LDS (full-line).
// ---------------------------------------------------------------------------
__global__ __launch_bounds__(256) void build_embed_kernel(
        const float* __restrict__ Xf, const ushort* __restrict__ Wh,
        const float* __restrict__ bias, ushort* __restrict__ xH,
        const int* __restrict__ src, const int* __restrict__ dst,
        const float* __restrict__ ew, int* __restrict__ cursor,
        int2* __restrict__ es2, int bucketMode, int M) {
    __shared__ ushort Xs[128 * 128];          // 32 KB (embed blocks only)
    const int tid = threadIdx.x;

    if (blockIdx.x >= GEMM_BLOCKS) {
        // ---- scatter role: 4 strided edges/thread ----
        int base = (blockIdx.x - GEMM_BLOCKS) * 1024 + tid;
#pragma unroll
        for (int k = 0; k < 4; ++k) {
            int e = base + k * 256;
            if (e < E_EDGES) {
                int d = dst[e];
                int pos = atomicAdd(&cursor[d], 1);
                int2 rec = make_int2(src[e], __float_as_int(ew[e]));
                if (bucketMode) {
                    if (pos < MAXDEG) es2[d * MAXDEG + pos] = rec;
                } else {
                    es2[pos] = rec;
                }
            }
        }
        return;
    }

    // ---- embed role ----
    const int rowBase = blockIdx.x * 128;
#pragma unroll
    for (int p = 0; p < 8; ++p) {
        int cid = p * 256 + tid;
        int r = cid >> 4, c8 = cid & 15;
        int gr = rowBase + r;
        uint4 val = make_uint4(0, 0, 0, 0);
        if (gr < M) {
            const float* ptr = Xf + (size_t)gr * 128 + c8 * 8;
            float4 f0 = *(const float4*)ptr;
            float4 f1 = *(const float4*)(ptr + 4);
            val.x = (uint)f2bf(f0.x) | ((uint)f2bf(f0.y) << 16);
            val.y = (uint)f2bf(f0.z) | ((uint)f2bf(f0.w) << 16);
            val.z = (uint)f2bf(f1.x) | ((uint)f2bf(f1.y) << 16);
            val.w = (uint)f2bf(f1.z) | ((uint)f2bf(f1.w) << 16);
        }
        *(uint4*)(Xs + r * 128 + ((c8 ^ (r & 7)) << 3)) = val;
    }
    __syncthreads();

    const int lane = tid & 63;
    const int wv = tid >> 6;
    const int wrow = (wv & 1) * 64;
    const int wcol = (wv >> 1) * 64;
    const int l16 = lane & 15;
    const int q = lane >> 4;

    v4f acc[4][4];
#pragma unroll
    for (int i = 0; i < 4; ++i)
#pragma unroll
        for (int j = 0; j < 4; ++j) { v4f z = {0.f,0.f,0.f,0.f}; acc[i][j] = z; }

#pragma unroll
    for (int ks = 0; ks < 4; ++ks) {
        const int chunk = ks * 4 + q;
        v8s a[4], b[4];
#pragma unroll
        for (int i = 0; i < 4; ++i) {
            int m = wrow + i * 16 + l16;
            a[i] = *(const v8s*)(Xs + m * 128 + ((chunk ^ (m & 7)) << 3));
        }
#pragma unroll
        for (int j = 0; j < 4; ++j)
            b[j] = *(const v8s*)(Wh + (size_t)(wcol + j * 16 + l16) * 128 + chunk * 8);
#pragma unroll
        for (int i = 0; i < 4; ++i)
#pragma unroll
            for (int j = 0; j < 4; ++j)
                acc[i][j] = __builtin_amdgcn_mfma_f32_16x16x32_bf16(a[i], b[j], acc[i][j], 0, 0, 0);
    }

    // all waves done reading Xs before C overwrites it
    __syncthreads();

    // ---- C -> Xs (swizzled, bias applied) ----
#pragma unroll
    for (int j = 0; j < 4; ++j) {
        int col = wcol + j * 16 + l16;
        float bj = bias[col];
        const int csw = col >> 3, clo = col & 7;
#pragma unroll
        for (int i = 0; i < 4; ++i) {
            int trB = wrow + i * 16 + q * 4;
#pragma unroll
            for (int r = 0; r < 4; ++r) {
                int tr = trB + r;
                Xs[tr * 128 + (((csw ^ (tr & 7)) << 3) | clo)] = f2bf(acc[i][j][r] + bj);
            }
        }
    }
    __syncthreads();

    // ---- coalesced stage-out: full 64B lines ----
#pragma unroll
    for (int p = 0; p < 8; ++p) {
        int cid = p * 256 + tid;              // 2048 uint4
        int r = cid >> 4, c8 = cid & 15;
        int gr = rowBase + r;
        if (gr < M) {
            uint4 val = *(const uint4*)(Xs + r * 128 + ((c8 ^ (r & 7)) << 3));
            *(uint4*)(xH + (size_t)gr * 128 + c8 * 8) = val;
        }
    }
}

// ---------------------------------------------------------------------------
// FUSED per-iteration kernel (r12-proven optimum): 64-row tiles, 512 threads,
// depth-4 gather, LDS stage-out for xout (full-line writes).
// Bracketed A/Bs: 32-row (r8) worse via traffic; 48-row (r13) worse via
// VGPR/ILP + pass-imbalance. This config: 48.1us, 1.83 TB/s effective.
// ---------------------------------------------------------------------------
__global__ __launch_bounds__(512) void gather_conv_update(
        const ushort* __restrict__ xin, ushort* __restrict__ xout,
        const int2* __restrict__ es2, const int* __restrict__ rowStart,
        const int* __restrict__ rowEnd, const ushort* __restrict__ Wcat2,
        const float* __restrict__ bconv, const ushort* __restrict__ WoutH,
        const float* __restrict__ bout, float* __restrict__ out,
        int doOut, int bucketMode, int esCap, int M) {
    __shared__ ushort Xs0[64 * 128];          // agg tile -> x_new tile (16 KB)
    __shared__ ushort Xs1[64 * 128];          // xin tile             (16 KB)
    const int tid = threadIdx.x;
    const int rowBase = blockIdx.x * 64;

    // ---- stage xin tile (coalesced, swizzled) ----
#pragma unroll
    for (int p = 0; p < 2; ++p) {
        int cid = p * 512 + tid;              // 1024 uint4
        int r = cid >> 4, c8 = cid & 15;
        int gr = rowBase + r;
        uint4 xv = make_uint4(0, 0, 0, 0);
        if (gr < M) xv = *(const uint4*)(xin + (size_t)gr * 128 + c8 * 8);
        *(uint4*)(Xs1 + r * 128 + ((c8 ^ (r & 7)) << 3)) = xv;
    }

    // ---- gather phase: 16 lanes/node, 32 groups, 2 passes ----
    const int q16 = tid & 15;                 // elems [q16*8, q16*8+8)
    const int nb = tid >> 4;                  // group id 0..31
    const int gb = tid & 48;                  // group-base lane within wave
    for (int pass = 0; pass < 2; ++pass) {
        int r = pass * 32 + nb;               // local row 0..63
        int gr = rowBase + r;
        float sA[8] = {0,0,0,0,0,0,0,0};
        float sB[8] = {0,0,0,0,0,0,0,0};
        int e0 = 0, deg = 0;
        if (gr < M) {
            if (bucketMode) { e0 = gr * MAXDEG; deg = rowEnd[gr]; }
            else            { e0 = rowStart[gr]; deg = rowEnd[gr] - e0; }
        }
        for (int base = 0; base < deg; base += 16) {
            // one coalesced bulk-load of up to 16 edge records for the group
            int idx = e0 + base + q16;
            int2 myE = es2[idx < esCap ? idx : esCap - 1];
            int cnt = deg - base; if (cnt > 16) cnt = 16;
            int k = 0;
            for (; k + 4 <= cnt; k += 4) {
                int s0 = __shfl(myE.x, gb + k + 0);
                int s1 = __shfl(myE.x, gb + k + 1);
                int s2 = __shfl(myE.x, gb + k + 2);
                int s3 = __shfl(myE.x, gb + k + 3);
                float w0 = __int_as_float(__shfl(myE.y, gb + k + 0));
                float w1 = __int_as_float(__shfl(myE.y, gb + k + 1));
                float w2 = __int_as_float(__shfl(myE.y, gb + k + 2));
                float w3 = __int_as_float(__shfl(myE.y, gb + k + 3));
                uint4 v0 = *(const uint4*)(xin + (size_t)s0 * 128 + q16 * 8);
                uint4 v1 = *(const uint4*)(xin + (size_t)s1 * 128 + q16 * 8);
                uint4 v2 = *(const uint4*)(xin + (size_t)s2 * 128 + q16 * 8);
                uint4 v3 = *(const uint4*)(xin + (size_t)s3 * 128 + q16 * 8);
                sA[0] = fmaf(w0, bflo(v0.x), sA[0]); sA[1] = fmaf(w0, bfhi(v0.x), sA[1]);
                sA[2] = fmaf(w0, bflo(v0.y), sA[2]); sA[3] = fmaf(w0, bfhi(v0.y), sA[3]);
                sA[4] = fmaf(w0, bflo(v0.z), sA[4]); sA[5] = fmaf(w0, bfhi(v0.z), sA[5]);
                sA[6] = fmaf(w0, bflo(v0.w), sA[6]); sA[7] = fmaf(w0, bfhi(v0.w), sA[7]);
                sB[0] = fmaf(w1, bflo(v1.x), sB[0]); sB[1] = fmaf(w1, bfhi(v1.x), sB[1]);
                sB[2] = fmaf(w1, bflo(v1.y), sB[2]); sB[3] = fmaf(w1, bfhi(v1.y), sB[3]);
                sB[4] = fmaf(w1, bflo(v1.z), sB[4]); sB[5] = fmaf(w1, bfhi(v1.z), sB[5]);
                sB[6] = fmaf(w1, bflo(v1.w), sB[6]); sB[7] = fmaf(w1, bfhi(v1.w), sB[7]);
                sA[0] = fmaf(w2, bflo(v2.x), sA[0]); sA[1] = fmaf(w2, bfhi(v2.x), sA[1]);
                sA[2] = fmaf(w2, bflo(v2.y), sA[2]); sA[3] = fmaf(w2, bfhi(v2.y), sA[3]);
                sA[4] = fmaf(w2, bflo(v2.z), sA[4]); sA[5] = fmaf(w2, bfhi(v2.z), sA[5]);
                sA[6] = fmaf(w2, bflo(v2.w), sA[6]); sA[7] = fmaf(w2, bfhi(v2.w), sA[7]);
                sB[0] = fmaf(w3, bflo(v3.x), sB[0]); sB[1] = fmaf(w3, bfhi(v3.x), sB[1]);
                sB[2] = fmaf(w3, bflo(v3.y), sB[2]); sB[3] = fmaf(w3, bfhi(v3.y), sB[3]);
                sB[4] = fmaf(w3, bflo(v3.z), sB[4]); sB[5] = fmaf(w3, bfhi(v3.z), sB[5]);
                sB[6] = fmaf(w3, bflo(v3.w), sB[6]); sB[7] = fmaf(w3, bfhi(v3.w), sB[7]);
            }
            for (; k < cnt; ++k) {
                int s = __shfl(myE.x, gb + k);
                float w = __int_as_float(__shfl(myE.y, gb + k));
                uint4 v = *(const uint4*)(xin + (size_t)s * 128 + q16 * 8);
                sA[0] = fmaf(w, bflo(v.x), sA[0]); sA[1] = fmaf(w, bfhi(v.x), sA[1]);
                sA[2] = fmaf(w, bflo(v.y), sA[2]); sA[3] = fmaf(w, bfhi(v.y), sA[3]);
                sA[4] = fmaf(w, bflo(v.z), sA[4]); sA[5] = fmaf(w, bfhi(v.z), sA[5]);
                sA[6] = fmaf(w, bflo(v.w), sA[6]); sA[7] = fmaf(w, bfhi(v.w), sA[7]);
            }
        }
        uint4 o;
        o.x = (uint)f2bf(sA[0] + sB[0]) | ((uint)f2bf(sA[1] + sB[1]) << 16);
        o.y = (uint)f2bf(sA[2] + sB[2]) | ((uint)f2bf(sA[3] + sB[3]) << 16);
        o.z = (uint)f2bf(sA[4] + sB[4]) | ((uint)f2bf(sA[5] + sB[5]) << 16);
        o.w = (uint)f2bf(sA[6] + sB[6]) | ((uint)f2bf(sA[7] + sB[7]) << 16);
        *(uint4*)(Xs0 + r * 128 + ((q16 ^ (r & 7)) << 3)) = o;
    }
    __syncthreads();

    const int lane = tid & 63;
    const int wv = tid >> 6;                  // wave col-block: cols [wv*16, wv*16+16)
    const int l16 = lane & 15;
    const int q = lane >> 4;

    v4f acc[4];
#pragma unroll
    for (int i = 0; i < 4; ++i) { v4f z = {0.f,0.f,0.f,0.f}; acc[i] = z; }

    // 8 K-chunks: ks<4 -> agg x W_lin (wOff=128); ks>=4 -> x x A (wOff=0)
#pragma unroll
    for (int ks = 0; ks < 8; ++ks) {
        const ushort* Xsrc = (ks < 4) ? Xs0 : Xs1;
        const int wOff = (ks < 4) ? 128 : 0;
        const int chunk = (ks & 3) * 4 + q;
        v8s a[4], b;
#pragma unroll
        for (int i = 0; i < 4; ++i) {
            int m = i * 16 + l16;             // rows 0..63
            a[i] = *(const v8s*)(Xsrc + m * 128 + ((chunk ^ (m & 7)) << 3));
        }
        b = *(const v8s*)(Wcat2 + (size_t)(wv * 16 + l16) * 256 + wOff + chunk * 8);
#pragma unroll
        for (int i = 0; i < 4; ++i)
            acc[i] = __builtin_amdgcn_mfma_f32_16x16x32_bf16(a[i], b, acc[i], 0, 0, 0);
    }

    // all waves done reading Xs0 (agg) before it is overwritten with x_new
    __syncthreads();

    // ---- epilogue: x-old from Xs1; h -> Xs0 (swizzled, same layout) ----
    {
        int col = wv * 16 + l16;
        float bj = bconv[col];
        const int csw = col >> 3, clo = col & 7;
#pragma unroll
        for (int i = 0; i < 4; ++i) {
            int trB = i * 16 + q * 4;
#pragma unroll
            for (int r = 0; r < 4; ++r) {
                int tr = trB + r;
                int li = tr * 128 + (((csw ^ (tr & 7)) << 3) | clo);
                float conv = acc[i][r] + bj;
                float xv = bf2f(Xs1[li]) + EPS_C * tanh_fast(conv);
                Xs0[li] = f2bf(xv);
            }
        }
    }
    __syncthreads();

    // ---- coalesced stage-out: full 64B lines (mirror of stage-in) ----
#pragma unroll
    for (int p = 0; p < 2; ++p) {
        int cid = p * 512 + tid;              // 1024 uint4
        int r = cid >> 4, c8 = cid & 15;
        int gr = rowBase + r;
        if (gr < M) {
            uint4 val = *(const uint4*)(Xs0 + r * 128 + ((c8 ^ (r & 7)) << 3));
            *(uint4*)(xout + (size_t)gr * 128 + c8 * 8) = val;
        }
    }

    if (doOut) {
        // Xs0 holds x_new (stage-out was read-only); readout from Xs0
        if (wv < 4) {
            v4f acc2[3];
#pragma unroll
            for (int j = 0; j < 3; ++j) { v4f z = {0.f,0.f,0.f,0.f}; acc2[j] = z; }

#pragma unroll
            for (int ks = 0; ks < 4; ++ks) {
                const int chunk = ks * 4 + q;
                int m = wv * 16 + l16;
                v8s a2 = *(const v8s*)(Xs0 + m * 128 + ((chunk ^ (m & 7)) << 3));
                v8s b2[3];
#pragma unroll
                for (int j = 0; j < 3; ++j)
                    b2[j] = *(const v8s*)(WoutH + (size_t)(j * 16 + l16) * 128 + chunk * 8);
#pragma unroll
                for (int j = 0; j < 3; ++j)
                    acc2[j] = __builtin_amdgcn_mfma_f32_16x16x32_bf16(a2, b2[j], acc2[j], 0, 0, 0);
            }

#pragma unroll
            for (int j = 0; j < 3; ++j) {
                int col = j * 16 + l16;
                if (col >= OUT_DIM) continue;
                float bj = bout[col];
                int grB = rowBase + wv * 16 + q * 4;
#pragma unroll
                for (int r = 0; r < 4; ++r) {
                    int gr = grB + r;
                    if (gr < M) out[(size_t)gr * OUT_DIM + col] = acc2[j][r] + bj;
                }
            }
        }
    }
}

// ---------------------------------------------------------------------------
// Exact-CSR fallback chain (used only if ws_size can't hold the buckets)
// ---------------------------------------------------------------------------
__global__ __launch_bounds__(256) void hist_kernel(const int* __restrict__ dst,
                                                   int* __restrict__ cnt) {
    int base = blockIdx.x * 1024 + threadIdx.x;
#pragma unroll
    for (int k = 0; k < 4; ++k) {
        int e = base + k * 256;
        if (e < E_EDGES) atomicAdd(&cnt[dst[e]], 1);
    }
}

__global__ __launch_bounds__(256) void scan_phase1(const int* __restrict__ deg,
                                                   int* __restrict__ localEx,
                                                   int* __restrict__ blockSums) {
    __shared__ int tmp[256];
    const int t = threadIdx.x;
    const int i = blockIdx.x * 256 + t;
    int v = (i < N_NODES) ? deg[i] : 0;
    tmp[t] = v;
    __syncthreads();
#pragma unroll
    for (int off = 1; off < 256; off <<= 1) {
        int u = (t >= off) ? tmp[t - off] : 0;
        __syncthreads();
        tmp[t] += u;
        __syncthreads();
    }
    if (i < N_NODES) localEx[i] = tmp[t] - v;
    if (t == 255) blockSums[blockIdx.x] = tmp[255];
}

__global__ __launch_bounds__(256) void scan_phase23(int* __restrict__ rowStart,
                                                    const int* __restrict__ blockSums,
                                                    int* __restrict__ cursor) {
    __shared__ int tmp[256];
    __shared__ int offs;
    const int t = threadIdx.x;
    int v = (t < SCAN_BLOCKS) ? blockSums[t] : 0;
    tmp[t] = v;
    __syncthreads();
#pragma unroll
    for (int off = 1; off < 256; off <<= 1) {
        int u = (t >= off) ? tmp[t - off] : 0;
        __syncthreads();
        tmp[t] += u;
        __syncthreads();
    }
    if (t == blockIdx.x) offs = tmp[t] - v;
    __syncthreads();
    const int i = blockIdx.x * 256 + t;
    if (i < N_NODES) {
        int val = rowStart[i] + offs;
        rowStart[i] = val;
        cursor[i] = val;
    }
}

extern "C" void kernel_launch(void* const* d_in, const int* in_sizes, int n_in,
                              void* d_out, int out_size, void* d_ws, size_t ws_size,
                              hipStream_t stream) {
    const float* x_in   = (const float*)d_in[0];
    const int*   ei     = (const int*)  d_in[1];   // (2,E) int32: src=ei, dst=ei+E
    const float* ew     = (const float*)d_in[2];
    const float* W_emb  = (const float*)d_in[3];
    const float* b_emb  = (const float*)d_in[4];
    const float* W_lin  = (const float*)d_in[5];
    const float* W_anti = (const float*)d_in[6];
    const float* b_conv = (const float*)d_in[7];
    const float* W_out  = (const float*)d_in[8];
    const float* b_out  = (const float*)d_in[9];
    float* out = (float*)d_out;

    // workspace: xhA | xhB | WembH | Wcat2H | WoutH | rowStart | cursor |
    //            es2 (bucket: N*MAXDEG int2 = 19.2MB; CSR: E int2) | blockSums
    ushort* xhA    = (ushort*)d_ws;
    ushort* xhB    = xhA + (size_t)N_NODES * D_DIM;
    ushort* WembH  = xhB + (size_t)N_NODES * D_DIM;
    ushort* Wcat2H = WembH + D_DIM * D_DIM;
    ushort* WoutH  = Wcat2H + 2 * D_DIM * D_DIM;
    int*    rowStart = (int*)(WoutH + 48 * D_DIM);
    int*    cursor   = rowStart + N_NODES;
    int2*   es2      = (int2*)(cursor + N_NODES);
    int*    blockSums = (int*)(es2 + E_EDGES);   // CSR mode only

    const int* src = ei;
    const int* dst = ei + E_EDGES;

    // bucket layout fits? fixed prefix + N*MAXDEG records (+ slack)
    size_t fixedBytes = (size_t)((char*)es2 - (char*)d_ws);
    size_t bucketBytes = (size_t)N_NODES * MAXDEG * sizeof(int2);
    int bucket = (ws_size >= fixedBytes + bucketBytes + 4096) ? 1 : 0;
    int esCap = bucket ? N_NODES * MAXDEG : E_EDGES;

    // ---- front-end ----
    zero_prep_kernel<<<SCAN_BLOCKS, 256, 0, stream>>>(cursor, W_emb, W_lin, W_anti,
                                                      W_out, WembH, Wcat2H, WoutH);
    if (!bucket) {
        hist_kernel<<<EDGE_BLOCKS_C, 256, 0, stream>>>(dst, cursor);
        scan_phase1<<<SCAN_BLOCKS, 256, 0, stream>>>(cursor, rowStart, blockSums);
        scan_phase23<<<SCAN_BLOCKS, 256, 0, stream>>>(rowStart, blockSums, cursor);
    }
    build_embed_kernel<<<GEMM_BLOCKS + EDGE_BLOCKS_C, 256, 0, stream>>>(
        x_in, WembH, b_emb, xhA, src, dst, ew, cursor, es2, bucket, N_NODES);
    // after build: bucket -> cursor[d] = degree; CSR -> cursor[d] = row end

    // ---- iterations: ONE fused dispatch each, ping-pong xhA/xhB ----
    ushort* bufs[2] = { xhA, xhB };
    for (int it = 0; it < N_ITERS; ++it) {
        gather_conv_update<<<CONV_BLOCKS, 512, 0, stream>>>(
            bufs[it & 1], bufs[(it + 1) & 1], es2, rowStart, cursor,
            Wcat2H, b_conv, WoutH, b_out, out,
            (it == N_ITERS - 1) ? 1 : 0, bucket, esCap, N_NODES);
    }
}